// Round 1
// baseline (302.120 us; speedup 1.0000x reference)
//
#include <hip/hip_runtime.h>
#include <hip/hip_bf16.h>

typedef __bf16 bf16x8 __attribute__((ext_vector_type(8)));
typedef float f32x4 __attribute__((ext_vector_type(4)));

// Problem constants
#define SEQ   2048
#define NB    2
#define NTOK  4096        // NB*SEQ
#define HIDD  512
#define NHEAD 16
#define DHEAD 64
#define QKVN  3072        // 3 * NHEAD*DHEAD
#define GUN   2048        // gate(1024) + up(1024)

// ---------------- workspace layout (bytes) ----------------
#define OFF_WQKVT  0u                       // [3072][512] bf16  = 3,145,728
#define OFF_WOT    3145728u                 // [512][1024] bf16  = 1,048,576
#define OFF_WGUT   4194304u                 // [2048][512] bf16  = 2,097,152
#define OFF_WDT    6291456u                 // [512][1024] bf16  = 1,048,576
#define OFF_HB     7340032u                 // [4096][512] bf16  = 4,194,304
#define OFF_QKV    11534336u                // [4096][3072] bf16 = 25,165,824
#define OFF_ATTN   36700160u                // [4096][1024] bf16 = 8,388,608
#define OFF_H2     45088768u                // [4096][512] f32   = 8,388,608
#define OFF_G      53477376u                // [4096][512] bf16  = 4,194,304
// region reuse (qkv dead after attention):
#define OFF_GU     OFF_QKV                  // [4096][2048] bf16 = 16,777,216
#define OFF_M      (OFF_QKV + 16777216u)    // [4096][1024] bf16 = 8,388,608

// ---------------- weight transpose + f32->bf16 ----------------
// in: [K][N] f32, out: [N][K] bf16
__global__ void conv_t_k(const float* __restrict__ in, __bf16* __restrict__ out,
                         int K, int N) {
    int idx = blockIdx.x * 256 + threadIdx.x;
    if (idx >= N * K) return;
    int n = idx / K, k = idx % K;
    out[idx] = (__bf16)in[(size_t)k * N + n];
}

// ---------------- RMSNorm: f32 in -> bf16 out (row = 512) ----------------
__global__ __launch_bounds__(256) void rmsnorm_k(const float* __restrict__ x,
                                                 const float* __restrict__ w,
                                                 __bf16* __restrict__ out) {
    int row = blockIdx.x;
    int t = threadIdx.x;
    const float* xr = x + (size_t)row * HIDD;
    float2 v = *(const float2*)&xr[t * 2];
    float ss = v.x * v.x + v.y * v.y;
#pragma unroll
    for (int off = 32; off >= 1; off >>= 1) ss += __shfl_xor(ss, off);
    __shared__ float red[4];
    if ((t & 63) == 0) red[t >> 6] = ss;
    __syncthreads();
    float tot = red[0] + red[1] + red[2] + red[3];
    float r = rsqrtf(tot * (1.0f / HIDD) + 1e-8f);
    out[(size_t)row * HIDD + t * 2]     = (__bf16)(v.x * r * w[t * 2]);
    out[(size_t)row * HIDD + t * 2 + 1] = (__bf16)(v.y * r * w[t * 2 + 1]);
}

// ---------------- GEMM: C[M][N] = A[M][K] * Bt[N][K]^T ----------------
// EPI 0: C -> bf16 buffer.  EPI 2: Cf = resid + acc*scale[col] (f32 out)
template <int EPI>
__global__ __launch_bounds__(256) void gemm_bt(const __bf16* __restrict__ A,
                                               const __bf16* __restrict__ Bt,
                                               int M, int N, int K,
                                               __bf16* __restrict__ Cb,
                                               float* __restrict__ Cf,
                                               const float* __restrict__ resid,
                                               const float* __restrict__ scale) {
    __shared__ alignas(16) __bf16 As[128][32];
    __shared__ alignas(16) __bf16 Bs[128][32];
    int m0 = blockIdx.y * 128, n0 = blockIdx.x * 128;
    int tid = threadIdx.x;
    int lane = tid & 63, w = tid >> 6;
    int wm = (w >> 1) * 64, wn = (w & 1) * 64;
    int lr = lane & 15, lkg = lane >> 4, lk = lkg * 8;
    f32x4 acc[4][4] = {};
    int nkt = K >> 5;
    for (int kt = 0; kt < nkt; ++kt) {
        __syncthreads();
#pragma unroll
        for (int i = 0; i < 2; ++i) {
            int c = tid + i * 256;
            int row = c >> 2, k8 = (c & 3) << 3;
            *(uint4*)&As[row][k8] =
                *(const uint4*)&A[(size_t)(m0 + row) * K + kt * 32 + k8];
            *(uint4*)&Bs[row][k8] =
                *(const uint4*)&Bt[(size_t)(n0 + row) * K + kt * 32 + k8];
        }
        __syncthreads();
        bf16x8 af[4], bfv[4];
#pragma unroll
        for (int mi = 0; mi < 4; ++mi) af[mi] = *(const bf16x8*)&As[wm + mi * 16 + lr][lk];
#pragma unroll
        for (int ni = 0; ni < 4; ++ni) bfv[ni] = *(const bf16x8*)&Bs[wn + ni * 16 + lr][lk];
#pragma unroll
        for (int mi = 0; mi < 4; ++mi)
#pragma unroll
            for (int ni = 0; ni < 4; ++ni)
                acc[mi][ni] = __builtin_amdgcn_mfma_f32_16x16x32_bf16(
                    af[mi], bfv[ni], acc[mi][ni], 0, 0, 0);
    }
#pragma unroll
    for (int mi = 0; mi < 4; ++mi)
#pragma unroll
        for (int ni = 0; ni < 4; ++ni)
#pragma unroll
            for (int r = 0; r < 4; ++r) {
                int row = m0 + wm + mi * 16 + lkg * 4 + r;
                int col = n0 + wn + ni * 16 + lr;
                size_t idx = (size_t)row * N + col;
                float vv = acc[mi][ni][r];
                if (EPI == 0) Cb[idx] = (__bf16)vv;
                else          Cf[idx] = resid[idx] + vv * scale[col];
            }
}

// ---------------- RoPE in-place on q,k halves of qkv ----------------
__global__ void rope_k(__bf16* __restrict__ qkv, const float* __restrict__ cosv,
                       const float* __restrict__ sinv) {
    int idx = blockIdx.x * 256 + threadIdx.x;  // NTOK*512
    int tok = idx >> 9;
    int rem = idx & 511;
    int h = rem >> 5, d = rem & 31;
    int s = tok & (SEQ - 1);
    float c = cosv[s * 32 + d], sn = sinv[s * 32 + d];
    size_t base = (size_t)tok * QKVN + h * 64 + d;
    float q1 = (float)qkv[base], q2 = (float)qkv[base + 32];
    qkv[base]      = (__bf16)(q1 * c - q2 * sn);
    qkv[base + 32] = (__bf16)(q2 * c + q1 * sn);
    float k1 = (float)qkv[base + 1024], k2 = (float)qkv[base + 1056];
    qkv[base + 1024] = (__bf16)(k1 * c - k2 * sn);
    qkv[base + 1056] = (__bf16)(k2 * c + k1 * sn);
}

// ---------------- causal flash attention ----------------
// grid.x = NB*NHEAD (32), grid.y = SEQ/64 (32). 4 waves x 16 q-rows.
__global__ __launch_bounds__(256) void attn_k(const __bf16* __restrict__ qkv,
                                              __bf16* __restrict__ outp) {
    __shared__ alignas(16) __bf16 Kt[32][64];
    __shared__ alignas(16) __bf16 VT[64][32];
    __shared__ alignas(16) __bf16 Pl[4][16][32];
    int bh = blockIdx.x;
    int b = bh >> 4, h = bh & 15;
    int qb = blockIdx.y;
    int tid = threadIdx.x, lane = tid & 63, w = tid >> 6;
    int lr = lane & 15, lkg = lane >> 4, lk = lkg * 8;
    int qr0 = qb * 64 + w * 16;
    size_t tokb = (size_t)b * SEQ;

    bf16x8 aq[2];
#pragma unroll
    for (int ks = 0; ks < 2; ++ks)
        aq[ks] = *(const bf16x8*)&qkv[(tokb + qr0 + lr) * QKVN + h * 64 + ks * 32 + lk];

    f32x4 oa[4] = {};
    float m_run[4], l_run[4];
#pragma unroll
    for (int r = 0; r < 4; ++r) { m_run[r] = -1e30f; l_run[r] = 0.0f; }

    int nkb = (qb + 1) * 2;
    for (int kb = 0; kb < nkb; ++kb) {
        __syncthreads();
        {   // stage K tile and transposed V tile
            int key = tid >> 3, ch = tid & 7;
            size_t rowb = (tokb + kb * 32 + key) * QKVN + h * 64 + ch * 8;
            *(uint4*)&Kt[key][ch * 8] = *(const uint4*)&qkv[rowb + 1024];
            uint4 vv = *(const uint4*)&qkv[rowb + 2048];
            const __bf16* ve = (const __bf16*)&vv;
#pragma unroll
            for (int j = 0; j < 8; ++j) VT[ch * 8 + j][key] = ve[j];
        }
        __syncthreads();

        f32x4 sc[2] = {};
#pragma unroll
        for (int jt = 0; jt < 2; ++jt)
#pragma unroll
            for (int ks = 0; ks < 2; ++ks) {
                bf16x8 bk = *(const bf16x8*)&Kt[jt * 16 + lr][ks * 32 + lk];
                sc[jt] = __builtin_amdgcn_mfma_f32_16x16x32_bf16(aq[ks], bk, sc[jt], 0, 0, 0);
            }
        // scale + causal mask
#pragma unroll
        for (int jt = 0; jt < 2; ++jt)
#pragma unroll
            for (int r = 0; r < 4; ++r) {
                int q = qr0 + lkg * 4 + r;
                int key = kb * 32 + jt * 16 + lr;
                sc[jt][r] = sc[jt][r] * 0.125f + (key > q ? -1e9f : 0.0f);
            }
        // online softmax
        float al[4], rs[4];
#pragma unroll
        for (int r = 0; r < 4; ++r) {
            float v = fmaxf(sc[0][r], sc[1][r]);
            v = fmaxf(v, __shfl_xor(v, 1));
            v = fmaxf(v, __shfl_xor(v, 2));
            v = fmaxf(v, __shfl_xor(v, 4));
            v = fmaxf(v, __shfl_xor(v, 8));
            float mn = fmaxf(m_run[r], v);
            al[r] = __expf(m_run[r] - mn);
            m_run[r] = mn;
            rs[r] = 0.0f;
        }
#pragma unroll
        for (int jt = 0; jt < 2; ++jt)
#pragma unroll
            for (int r = 0; r < 4; ++r) {
                float p = __expf(sc[jt][r] - m_run[r]);
                sc[jt][r] = p;
                rs[r] += p;
            }
#pragma unroll
        for (int r = 0; r < 4; ++r) {
            float s = rs[r];
            s += __shfl_xor(s, 1);
            s += __shfl_xor(s, 2);
            s += __shfl_xor(s, 4);
            s += __shfl_xor(s, 8);
            l_run[r] = l_run[r] * al[r] + s;
        }
#pragma unroll
        for (int dt = 0; dt < 4; ++dt)
#pragma unroll
            for (int r = 0; r < 4; ++r) oa[dt][r] *= al[r];
        // P -> LDS (per-wave region)
#pragma unroll
        for (int jt = 0; jt < 2; ++jt)
#pragma unroll
            for (int r = 0; r < 4; ++r)
                Pl[w][lkg * 4 + r][jt * 16 + lr] = (__bf16)sc[jt][r];
        asm volatile("s_waitcnt lgkmcnt(0)" ::: "memory");
        bf16x8 ap = *(const bf16x8*)&Pl[w][lr][lk];
#pragma unroll
        for (int dt = 0; dt < 4; ++dt) {
            bf16x8 bv = *(const bf16x8*)&VT[dt * 16 + lr][lk];
            oa[dt] = __builtin_amdgcn_mfma_f32_16x16x32_bf16(ap, bv, oa[dt], 0, 0, 0);
        }
    }
#pragma unroll
    for (int dt = 0; dt < 4; ++dt)
#pragma unroll
        for (int r = 0; r < 4; ++r) {
            int row = qr0 + lkg * 4 + r;
            outp[(tokb + row) * 1024 + h * 64 + dt * 16 + lr] =
                (__bf16)(oa[dt][r] / l_run[r]);
        }
}

// ---------------- SiLU(gate) * up ----------------
__global__ void silu_mul_k(const __bf16* __restrict__ gu, __bf16* __restrict__ m) {
    int idx = blockIdx.x * 256 + threadIdx.x;  // NTOK*1024
    int row = idx >> 10, n = idx & 1023;
    float g = (float)gu[(size_t)row * GUN + n];
    float u = (float)gu[(size_t)row * GUN + 1024 + n];
    m[idx] = (__bf16)((g / (1.0f + __expf(-g))) * u);
}

// ---------------- launch ----------------
extern "C" void kernel_launch(void* const* d_in, const int* in_sizes, int n_in,
                              void* d_out, int out_size, void* d_ws, size_t ws_size,
                              hipStream_t stream) {
    const float* x       = (const float*)d_in[0];
    const float* cosv    = (const float*)d_in[1];
    const float* sinv    = (const float*)d_in[2];
    const float* wq      = (const float*)d_in[4];
    const float* wk      = (const float*)d_in[5];
    const float* wv      = (const float*)d_in[6];
    const float* wo      = (const float*)d_in[7];
    const float* wgate   = (const float*)d_in[8];
    const float* wup     = (const float*)d_in[9];
    const float* wdown   = (const float*)d_in[10];
    const float* norm1   = (const float*)d_in[11];
    const float* norm2   = (const float*)d_in[12];
    const float* ls_attn = (const float*)d_in[13];
    const float* ls_mlp  = (const float*)d_in[14];

    char* ws = (char*)d_ws;
    __bf16* wqkvT = (__bf16*)(ws + OFF_WQKVT);
    __bf16* woT   = (__bf16*)(ws + OFF_WOT);
    __bf16* wguT  = (__bf16*)(ws + OFF_WGUT);
    __bf16* wdT   = (__bf16*)(ws + OFF_WDT);
    __bf16* hb    = (__bf16*)(ws + OFF_HB);
    __bf16* qkvb  = (__bf16*)(ws + OFF_QKV);
    __bf16* attnb = (__bf16*)(ws + OFF_ATTN);
    float*  h2    = (float*)(ws + OFF_H2);
    __bf16* gb    = (__bf16*)(ws + OFF_G);
    __bf16* gub   = (__bf16*)(ws + OFF_GU);
    __bf16* mb    = (__bf16*)(ws + OFF_M);
    float*  outf  = (float*)d_out;

    // weights -> bf16 transposed
    conv_t_k<<<2048, 256, 0, stream>>>(wq, wqkvT, 512, 1024);
    conv_t_k<<<2048, 256, 0, stream>>>(wk, wqkvT + 1024 * 512, 512, 1024);
    conv_t_k<<<2048, 256, 0, stream>>>(wv, wqkvT + 2048 * 512, 512, 1024);
    conv_t_k<<<2048, 256, 0, stream>>>(wo, woT, 1024, 512);
    conv_t_k<<<2048, 256, 0, stream>>>(wgate, wguT, 512, 1024);
    conv_t_k<<<2048, 256, 0, stream>>>(wup, wguT + 1024 * 512, 512, 1024);
    conv_t_k<<<2048, 256, 0, stream>>>(wdown, wdT, 1024, 512);

    rmsnorm_k<<<NTOK, 256, 0, stream>>>(x, norm1, hb);
    gemm_bt<0><<<dim3(QKVN / 128, NTOK / 128), 256, 0, stream>>>(
        hb, wqkvT, NTOK, QKVN, 512, qkvb, nullptr, nullptr, nullptr);
    rope_k<<<NTOK * 512 / 256, 256, 0, stream>>>(qkvb, cosv, sinv);
    attn_k<<<dim3(NB * NHEAD, SEQ / 64), 256, 0, stream>>>(qkvb, attnb);
    gemm_bt<2><<<dim3(HIDD / 128, NTOK / 128), 256, 0, stream>>>(
        attnb, woT, NTOK, HIDD, 1024, nullptr, h2, x, ls_attn);
    rmsnorm_k<<<NTOK, 256, 0, stream>>>(h2, norm2, gb);
    gemm_bt<0><<<dim3(GUN / 128, NTOK / 128), 256, 0, stream>>>(
        gb, wguT, NTOK, GUN, 512, gub, nullptr, nullptr, nullptr);
    silu_mul_k<<<NTOK * 1024 / 256, 256, 0, stream>>>(gub, mb);
    gemm_bt<2><<<dim3(HIDD / 128, NTOK / 128), 256, 0, stream>>>(
        mb, wdT, NTOK, HIDD, 1024, nullptr, outf, h2, ls_mlp);
}

// Round 2
// 188.022 us; speedup vs baseline: 1.6068x; 1.6068x over previous
//
#include <hip/hip_runtime.h>
#include <hip/hip_bf16.h>

typedef __bf16 bf16x8 __attribute__((ext_vector_type(8)));
typedef float f32x4 __attribute__((ext_vector_type(4)));

#define SEQ   2048
#define NB    2
#define NTOK  4096
#define HIDD  512
#define NHEAD 16
#define DHEAD 64
#define QKVN  3072
#define GUN   2048

// workspace layout (bytes)
#define OFF_WQKVT  0u                       // [3072][512] bf16
#define OFF_WOT    3145728u                 // [512][1024] bf16
#define OFF_WGUT   4194304u                 // [2048][512] bf16 (gate/up interleaved by 16)
#define OFF_WDT    6291456u                 // [512][1024] bf16
#define OFF_HB     7340032u                 // [4096][512] bf16
#define OFF_QKV    11534336u                // [4096][3072] bf16 (roped in epilogue)
#define OFF_ATTN   36700160u                // [4096][1024] bf16
#define OFF_H2     45088768u                // [4096][512] f32
#define OFF_G      53477376u                // [4096][512] bf16
#define OFF_M      (OFF_QKV + 16777216u)    // [4096][1024] bf16 (reuses dead qkv tail)

// ---- global_load_lds helper (16B) ----
typedef unsigned int __attribute__((address_space(1))) as1_uint;
typedef unsigned int __attribute__((address_space(3))) as3_uint;
__device__ __forceinline__ void gload16(const void* g, void* l) {
    __builtin_amdgcn_global_load_lds((const as1_uint*)g, (as3_uint*)l, 16, 0, 0);
}

// ---------------- tiled transpose f32[K][N] -> bf16[N'][K] ----------------
// mode 0: out row = n.  mode 1: out row = (n>>4)*32 + phase*16 + (n&15)
__global__ __launch_bounds__(256) void transpose_k(const float* __restrict__ in,
                                                   __bf16* __restrict__ out,
                                                   int K, int N, int mode, int phase) {
    __shared__ float t[32][33];
    int n0 = blockIdx.x * 32, k0 = blockIdx.y * 32;
    int tx = threadIdx.x & 31, ty = threadIdx.x >> 5;  // ty 0..7
#pragma unroll
    for (int j = 0; j < 4; ++j)
        t[ty * 4 + j][tx] = in[(size_t)(k0 + ty * 4 + j) * N + n0 + tx];
    __syncthreads();
#pragma unroll
    for (int j = 0; j < 4; ++j) {
        int n = n0 + ty * 4 + j;
        int row = mode ? (((n >> 4) << 5) + phase * 16 + (n & 15)) : n;
        out[(size_t)row * K + k0 + tx] = (__bf16)t[tx][ty * 4 + j];
    }
}

// ---------------- RMSNorm: f32 in -> bf16 out ----------------
__global__ __launch_bounds__(256) void rmsnorm_k(const float* __restrict__ x,
                                                 const float* __restrict__ w,
                                                 __bf16* __restrict__ out) {
    int row = blockIdx.x;
    int t = threadIdx.x;
    const float* xr = x + (size_t)row * HIDD;
    float2 v = *(const float2*)&xr[t * 2];
    float ss = v.x * v.x + v.y * v.y;
#pragma unroll
    for (int off = 32; off >= 1; off >>= 1) ss += __shfl_xor(ss, off);
    __shared__ float red[4];
    if ((t & 63) == 0) red[t >> 6] = ss;
    __syncthreads();
    float tot = red[0] + red[1] + red[2] + red[3];
    float r = rsqrtf(tot * (1.0f / HIDD) + 1e-8f);
    out[(size_t)row * HIDD + t * 2]     = (__bf16)(v.x * r * w[t * 2]);
    out[(size_t)row * HIDD + t * 2 + 1] = (__bf16)(v.y * r * w[t * 2 + 1]);
}

// ---------------- GEMM: C[M][N] = A[M][K] * Bt[N][K]^T ----------------
// EPI 0: bf16 store. EPI 1: rope epilogue (QKV). EPI 2: f32 resid+scale.
// EPI 3: silu(gate)*up with interleaved-by-16 cols -> bf16 [M][N/2]
template <int EPI, int TM>
__global__ __launch_bounds__(256) void gemm_bt(const __bf16* __restrict__ A,
                                               const __bf16* __restrict__ Bt,
                                               int M, int N, int K,
                                               __bf16* __restrict__ Cb,
                                               float* __restrict__ Cf,
                                               const float* __restrict__ resid,
                                               const float* __restrict__ scale,
                                               const float* __restrict__ cosv,
                                               const float* __restrict__ sinv) {
    __shared__ alignas(16) __bf16 As[TM][32];
    __shared__ alignas(16) __bf16 Bs[128][32];
    constexpr int MI = TM / 32;                 // 4 (TM=128) or 2 (TM=64)
    int m0 = blockIdx.y * TM, n0 = blockIdx.x * 128;
    int tid = threadIdx.x;
    int lane = tid & 63, w = tid >> 6;
    int wm = (w >> 1) * (TM / 2), wn = (w & 1) * 64;
    int lr = lane & 15, lkg = lane >> 4, lk = lkg * 8;
    f32x4 acc[MI][4] = {};
    int nkt = K >> 5;
    for (int kt = 0; kt < nkt; ++kt) {
        __syncthreads();
#pragma unroll
        for (int i = 0; i < (TM * 4) / 256; ++i) {
            int c = i * 256 + tid;
            int row = c >> 2, k8 = (c & 3) << 3;
            gload16(&A[(size_t)(m0 + row) * K + kt * 32 + k8], &As[row][k8]);
        }
#pragma unroll
        for (int i = 0; i < 2; ++i) {
            int c = i * 256 + tid;
            int row = c >> 2, k8 = (c & 3) << 3;
            gload16(&Bt[(size_t)(n0 + row) * K + kt * 32 + k8], &Bs[row][k8]);
        }
        __syncthreads();
        bf16x8 af[MI], bfv[4];
#pragma unroll
        for (int mi = 0; mi < MI; ++mi) af[mi] = *(const bf16x8*)&As[wm + mi * 16 + lr][lk];
#pragma unroll
        for (int ni = 0; ni < 4; ++ni) bfv[ni] = *(const bf16x8*)&Bs[wn + ni * 16 + lr][lk];
#pragma unroll
        for (int mi = 0; mi < MI; ++mi)
#pragma unroll
            for (int ni = 0; ni < 4; ++ni)
                acc[mi][ni] = __builtin_amdgcn_mfma_f32_16x16x32_bf16(
                    af[mi], bfv[ni], acc[mi][ni], 0, 0, 0);
    }
    if (EPI == 1) {
        bool do_rope = (n0 + wn) < 2048;
#pragma unroll
        for (int mi = 0; mi < MI; ++mi)
#pragma unroll
            for (int r = 0; r < 4; ++r) {
                int row = m0 + wm + mi * 16 + lkg * 4 + r;
                int s = row & (SEQ - 1);
#pragma unroll
                for (int ni = 0; ni < 2; ++ni) {
                    float v1 = acc[mi][ni][r], v2 = acc[mi][ni + 2][r];
                    size_t i1 = (size_t)row * N + n0 + wn + ni * 16 + lr;
                    size_t i2 = i1 + 32;
                    if (do_rope) {
                        int d = ni * 16 + lr;
                        float c = cosv[s * 32 + d], sn = sinv[s * 32 + d];
                        Cb[i1] = (__bf16)(v1 * c - v2 * sn);
                        Cb[i2] = (__bf16)(v2 * c + v1 * sn);
                    } else {
                        Cb[i1] = (__bf16)v1;
                        Cb[i2] = (__bf16)v2;
                    }
                }
            }
    } else if (EPI == 3) {
#pragma unroll
        for (int mi = 0; mi < MI; ++mi)
#pragma unroll
            for (int r = 0; r < 4; ++r) {
                int row = m0 + wm + mi * 16 + lkg * 4 + r;
#pragma unroll
                for (int ni = 0; ni < 4; ni += 2) {
                    float g = acc[mi][ni][r], u = acc[mi][ni + 1][r];
                    float mv = (g / (1.0f + __expf(-g))) * u;
                    int j = (((n0 + wn + ni * 16) >> 5) << 4) + lr;
                    Cb[(size_t)row * 1024 + j] = (__bf16)mv;
                }
            }
    } else {
#pragma unroll
        for (int mi = 0; mi < MI; ++mi)
#pragma unroll
            for (int ni = 0; ni < 4; ++ni)
#pragma unroll
                for (int r = 0; r < 4; ++r) {
                    int row = m0 + wm + mi * 16 + lkg * 4 + r;
                    int col = n0 + wn + ni * 16 + lr;
                    size_t idx = (size_t)row * N + col;
                    float vv = acc[mi][ni][r];
                    if (EPI == 0) Cb[idx] = (__bf16)vv;
                    else          Cf[idx] = resid[idx] + vv * scale[col];
                }
    }
}

// ---------------- causal flash attention ----------------
// grid.x = NB*NHEAD, grid.y = SEQ/64 (heavy-first). 4 waves x 16 q-rows, KVBLK=64.
__global__ __launch_bounds__(256) void attn_k(const __bf16* __restrict__ qkv,
                                              __bf16* __restrict__ outp) {
    __shared__ alignas(16) __bf16 KtF[64 * 64];        // [key][d] slot-swizzled
    __shared__ alignas(16) __bf16 VtF[64 * 64];        // [d][key] slot-swizzled
    __shared__ alignas(16) __bf16 PlF[4 * 16 * 64];    // per-wave [q][key] swizzled
    int bh = blockIdx.x;
    int b = bh >> 4, h = bh & 15;
    int qb = (gridDim.y - 1) - blockIdx.y;             // heavy blocks first
    int tid = threadIdx.x, lane = tid & 63, w = tid >> 6;
    int lr = lane & 15, lkg = lane >> 4, lk = lkg * 8;
    int l7 = lr & 7;
    int qr0 = qb * 64 + w * 16;
    size_t tokb = (size_t)b * SEQ;

    bf16x8 aq[2];
#pragma unroll
    for (int ks = 0; ks < 2; ++ks)
        aq[ks] = *(const bf16x8*)&qkv[(tokb + qr0 + lr) * QKVN + h * 64 + ks * 32 + lk];

    f32x4 oa[4] = {};
    float m_run[4], l_run[4];
#pragma unroll
    for (int r = 0; r < 4; ++r) { m_run[r] = -1e30f; l_run[r] = 0.0f; }

    int nkb = qb + 1;
    for (int kb = 0; kb < nkb; ++kb) {
        __syncthreads();
        // K tile: global_load_lds, pre-swizzled source (slot ^= row&7)
#pragma unroll
        for (int i = 0; i < 2; ++i) {
            int c = i * 256 + tid;
            int kr = c >> 3, s = c & 7;
            gload16(&qkv[(tokb + kb * 64 + kr) * QKVN + 1024 + h * 64 + ((s ^ (kr & 7)) << 3)],
                    &KtF[c * 8]);
        }
        // V tile transposed: lane owns one key -> conflict-free swizzled writes
        {
            int key = lane;
            int kslot = key >> 3, ke = key & 7;
#pragma unroll
            for (int i = 0; i < 2; ++i) {
                int ch = w * 2 + i;  // 0..7
                uint4 vv = *(const uint4*)&qkv[(tokb + kb * 64 + key) * QKVN + 2048 + h * 64 + ch * 8];
                const __bf16* ve = (const __bf16*)&vv;
#pragma unroll
                for (int j = 0; j < 8; ++j) {
                    int row = ch * 8 + j;   // row&7 == j
                    VtF[row * 64 + ((kslot ^ j) << 3) + ke] = ve[j];
                }
            }
        }
        __syncthreads();

        // QK^T: 64 keys
        f32x4 sc[4] = {};
#pragma unroll
        for (int jt = 0; jt < 4; ++jt)
#pragma unroll
            for (int ks = 0; ks < 2; ++ks) {
                bf16x8 bk = *(const bf16x8*)&KtF[(jt * 16 + lr) * 64 + (((ks * 4 + lkg) ^ l7) << 3)];
                sc[jt] = __builtin_amdgcn_mfma_f32_16x16x32_bf16(aq[ks], bk, sc[jt], 0, 0, 0);
            }
        // scale + causal mask
#pragma unroll
        for (int jt = 0; jt < 4; ++jt)
#pragma unroll
            for (int r = 0; r < 4; ++r) {
                int q = qr0 + lkg * 4 + r;
                int key = kb * 64 + jt * 16 + lr;
                sc[jt][r] = sc[jt][r] * 0.125f + (key > q ? -1e9f : 0.0f);
            }
        // online softmax
        float al[4], rs[4];
#pragma unroll
        for (int r = 0; r < 4; ++r) {
            float v = fmaxf(fmaxf(sc[0][r], sc[1][r]), fmaxf(sc[2][r], sc[3][r]));
            v = fmaxf(v, __shfl_xor(v, 1));
            v = fmaxf(v, __shfl_xor(v, 2));
            v = fmaxf(v, __shfl_xor(v, 4));
            v = fmaxf(v, __shfl_xor(v, 8));
            float mn = fmaxf(m_run[r], v);
            al[r] = __expf(m_run[r] - mn);
            m_run[r] = mn;
            rs[r] = 0.0f;
        }
#pragma unroll
        for (int jt = 0; jt < 4; ++jt)
#pragma unroll
            for (int r = 0; r < 4; ++r) {
                float p = __expf(sc[jt][r] - m_run[r]);
                sc[jt][r] = p;
                rs[r] += p;
            }
#pragma unroll
        for (int r = 0; r < 4; ++r) {
            float s = rs[r];
            s += __shfl_xor(s, 1);
            s += __shfl_xor(s, 2);
            s += __shfl_xor(s, 4);
            s += __shfl_xor(s, 8);
            l_run[r] = l_run[r] * al[r] + s;
        }
#pragma unroll
        for (int dt = 0; dt < 4; ++dt)
#pragma unroll
            for (int r = 0; r < 4; ++r) oa[dt][r] *= al[r];
        // P -> LDS (per-wave region, swizzled)
#pragma unroll
        for (int jt = 0; jt < 4; ++jt)
#pragma unroll
            for (int r = 0; r < 4; ++r) {
                int rowp = lkg * 4 + r;
                PlF[w * 1024 + rowp * 64 + (((jt * 2 + (lr >> 3)) ^ (rowp & 7)) << 3) + l7] =
                    (__bf16)sc[jt][r];
            }
        asm volatile("s_waitcnt lgkmcnt(0)" ::: "memory");
        __builtin_amdgcn_sched_barrier(0);
        // P·V
#pragma unroll
        for (int ks2 = 0; ks2 < 2; ++ks2) {
            bf16x8 ap = *(const bf16x8*)&PlF[w * 1024 + lr * 64 + (((ks2 * 4 + lkg) ^ l7) << 3)];
#pragma unroll
            for (int dt = 0; dt < 4; ++dt) {
                bf16x8 bv = *(const bf16x8*)&VtF[(dt * 16 + lr) * 64 + (((ks2 * 4 + lkg) ^ l7) << 3)];
                oa[dt] = __builtin_amdgcn_mfma_f32_16x16x32_bf16(ap, bv, oa[dt], 0, 0, 0);
            }
        }
    }
#pragma unroll
    for (int dt = 0; dt < 4; ++dt)
#pragma unroll
        for (int r = 0; r < 4; ++r) {
            int row = qr0 + lkg * 4 + r;
            outp[(tokb + row) * 1024 + h * 64 + dt * 16 + lr] =
                (__bf16)(oa[dt][r] / l_run[r]);
        }
}

// ---------------- launch ----------------
extern "C" void kernel_launch(void* const* d_in, const int* in_sizes, int n_in,
                              void* d_out, int out_size, void* d_ws, size_t ws_size,
                              hipStream_t stream) {
    const float* x       = (const float*)d_in[0];
    const float* cosv    = (const float*)d_in[1];
    const float* sinv    = (const float*)d_in[2];
    const float* wq      = (const float*)d_in[4];
    const float* wk      = (const float*)d_in[5];
    const float* wv      = (const float*)d_in[6];
    const float* wo      = (const float*)d_in[7];
    const float* wgate   = (const float*)d_in[8];
    const float* wup     = (const float*)d_in[9];
    const float* wdown   = (const float*)d_in[10];
    const float* norm1   = (const float*)d_in[11];
    const float* norm2   = (const float*)d_in[12];
    const float* ls_attn = (const float*)d_in[13];
    const float* ls_mlp  = (const float*)d_in[14];

    char* ws = (char*)d_ws;
    __bf16* wqkvT = (__bf16*)(ws + OFF_WQKVT);
    __bf16* woT   = (__bf16*)(ws + OFF_WOT);
    __bf16* wguT  = (__bf16*)(ws + OFF_WGUT);
    __bf16* wdT   = (__bf16*)(ws + OFF_WDT);
    __bf16* hb    = (__bf16*)(ws + OFF_HB);
    __bf16* qkvb  = (__bf16*)(ws + OFF_QKV);
    __bf16* attnb = (__bf16*)(ws + OFF_ATTN);
    float*  h2    = (float*)(ws + OFF_H2);
    __bf16* gb    = (__bf16*)(ws + OFF_G);
    __bf16* mb    = (__bf16*)(ws + OFF_M);
    float*  outf  = (float*)d_out;

    // weights -> bf16 transposed (coalesced tiled transpose)
    transpose_k<<<dim3(32, 16), 256, 0, stream>>>(wq, wqkvT, 512, 1024, 0, 0);
    transpose_k<<<dim3(32, 16), 256, 0, stream>>>(wk, wqkvT + 1024 * 512, 512, 1024, 0, 0);
    transpose_k<<<dim3(32, 16), 256, 0, stream>>>(wv, wqkvT + 2048 * 512, 512, 1024, 0, 0);
    transpose_k<<<dim3(16, 32), 256, 0, stream>>>(wo, woT, 1024, 512, 0, 0);
    transpose_k<<<dim3(32, 16), 256, 0, stream>>>(wgate, wguT, 512, 1024, 1, 0);
    transpose_k<<<dim3(32, 16), 256, 0, stream>>>(wup, wguT, 512, 1024, 1, 1);
    transpose_k<<<dim3(16, 32), 256, 0, stream>>>(wdown, wdT, 1024, 512, 0, 0);

    rmsnorm_k<<<NTOK, 256, 0, stream>>>(x, norm1, hb);
    // QKV with fused RoPE epilogue
    gemm_bt<1, 128><<<dim3(QKVN / 128, NTOK / 128), 256, 0, stream>>>(
        hb, wqkvT, NTOK, QKVN, 512, qkvb, nullptr, nullptr, nullptr, cosv, sinv);
    attn_k<<<dim3(NB * NHEAD, SEQ / 64), 256, 0, stream>>>(qkvb, attnb);
    gemm_bt<2, 64><<<dim3(HIDD / 128, NTOK / 64), 256, 0, stream>>>(
        attnb, woT, NTOK, HIDD, 1024, nullptr, h2, x, ls_attn, nullptr, nullptr);
    rmsnorm_k<<<NTOK, 256, 0, stream>>>(h2, norm2, gb);
    // gate/up with fused SiLU*up epilogue (interleaved weight rows)
    gemm_bt<3, 128><<<dim3(GUN / 128, NTOK / 128), 256, 0, stream>>>(
        gb, wguT, NTOK, GUN, 512, mb, nullptr, nullptr, nullptr, nullptr, nullptr);
    gemm_bt<2, 64><<<dim3(HIDD / 128, NTOK / 64), 256, 0, stream>>>(
        mb, wdT, NTOK, HIDD, 1024, nullptr, outf, h2, ls_mlp, nullptr, nullptr);
}

// Round 3
// 176.260 us; speedup vs baseline: 1.7141x; 1.0667x over previous
//
#include <hip/hip_runtime.h>
#include <hip/hip_bf16.h>

typedef __bf16 bf16x8 __attribute__((ext_vector_type(8)));
typedef float f32x4 __attribute__((ext_vector_type(4)));

#define SEQ   2048
#define NB    2
#define NTOK  4096
#define HIDD  512
#define NHEAD 16
#define DHEAD 64
#define QKVN  3072
#define GUN   2048

// workspace layout (bytes)
#define OFF_WQKVT  0u                       // [3072][512] bf16
#define OFF_WOT    3145728u                 // [512][1024] bf16
#define OFF_WGUT   4194304u                 // [2048][512] bf16 (gate/up interleaved by 16)
#define OFF_WDT    6291456u                 // [512][1024] bf16
#define OFF_HB     7340032u                 // [4096][512] bf16
#define OFF_QKV    11534336u                // [4096][3072] bf16 (roped, q pre-scaled)
#define OFF_ATTN   36700160u                // [4096][1024] bf16
#define OFF_H2     45088768u                // [4096][512] f32
#define OFF_G      53477376u                // [4096][512] bf16
#define OFF_M      (OFF_QKV + 16777216u)    // [4096][1024] bf16 (reuses dead qkv tail)

#define QSCALE 0.1803368801111731f          // 0.125 * log2(e): exp2-domain scores

// ---- global_load_lds helper (16B) ----
typedef unsigned int __attribute__((address_space(1))) as1_uint;
typedef unsigned int __attribute__((address_space(3))) as3_uint;
__device__ __forceinline__ void gload16(const void* g, void* l) {
    __builtin_amdgcn_global_load_lds((const as1_uint*)g, (as3_uint*)l, 16, 0, 0);
}

// ---------------- all 7 weight transposes in one launch ----------------
// f32[K][N] -> bf16[N'][K]; mode 1 interleaves gate/up rows by 16.
__global__ __launch_bounds__(256) void transpose_all_k(
    const float* __restrict__ wq, const float* __restrict__ wk,
    const float* __restrict__ wv, const float* __restrict__ wo,
    const float* __restrict__ wg, const float* __restrict__ wu,
    const float* __restrict__ wd,
    __bf16* __restrict__ qkvT, __bf16* __restrict__ woT,
    __bf16* __restrict__ wguT, __bf16* __restrict__ wdT) {
    __shared__ float t[32][33];
    int which = blockIdx.y;
    const float* in; __bf16* out; int K, N, mode = 0, phase = 0;
    switch (which) {
        case 0: in = wq; out = qkvT;              K = 512;  N = 1024; break;
        case 1: in = wk; out = qkvT + 1024 * 512; K = 512;  N = 1024; break;
        case 2: in = wv; out = qkvT + 2048 * 512; K = 512;  N = 1024; break;
        case 3: in = wo; out = woT;               K = 1024; N = 512;  break;
        case 4: in = wg; out = wguT;              K = 512;  N = 1024; mode = 1; phase = 0; break;
        case 5: in = wu; out = wguT;              K = 512;  N = 1024; mode = 1; phase = 1; break;
        default: in = wd; out = wdT;              K = 1024; N = 512;  break;
    }
    int ntn = N >> 5;
    int n0 = (blockIdx.x & (ntn - 1)) * 32;
    int k0 = (blockIdx.x / ntn) * 32;
    int tx = threadIdx.x & 31, ty = threadIdx.x >> 5;
#pragma unroll
    for (int j = 0; j < 4; ++j)
        t[ty * 4 + j][tx] = in[(size_t)(k0 + ty * 4 + j) * N + n0 + tx];
    __syncthreads();
#pragma unroll
    for (int j = 0; j < 4; ++j) {
        int n = n0 + ty * 4 + j;
        int row = mode ? (((n >> 4) << 5) + phase * 16 + (n & 15)) : n;
        out[(size_t)row * K + k0 + tx] = (__bf16)t[tx][ty * 4 + j];
    }
}

// ---------------- RMSNorm: f32 in -> bf16 out ----------------
__global__ __launch_bounds__(256) void rmsnorm_k(const float* __restrict__ x,
                                                 const float* __restrict__ w,
                                                 __bf16* __restrict__ out) {
    int row = blockIdx.x;
    int t = threadIdx.x;
    const float* xr = x + (size_t)row * HIDD;
    float2 v = *(const float2*)&xr[t * 2];
    float ss = v.x * v.x + v.y * v.y;
#pragma unroll
    for (int off = 32; off >= 1; off >>= 1) ss += __shfl_xor(ss, off);
    __shared__ float red[4];
    if ((t & 63) == 0) red[t >> 6] = ss;
    __syncthreads();
    float tot = red[0] + red[1] + red[2] + red[3];
    float r = rsqrtf(tot * (1.0f / HIDD) + 1e-8f);
    out[(size_t)row * HIDD + t * 2]     = (__bf16)(v.x * r * w[t * 2]);
    out[(size_t)row * HIDD + t * 2 + 1] = (__bf16)(v.y * r * w[t * 2 + 1]);
}

// ---------------- GEMM: C[M][N] = A[M][K] * Bt[N][K]^T ----------------
// EPI 0: bf16 store. EPI 1: rope epilogue + q pre-scale (QKV).
// EPI 2: f32 resid+scale. EPI 3: silu(gate)*up interleaved -> bf16 [M][N/2]
template <int EPI, int TM>
__global__ __launch_bounds__(256) void gemm_bt(const __bf16* __restrict__ A,
                                               const __bf16* __restrict__ Bt,
                                               int M, int N, int K,
                                               __bf16* __restrict__ Cb,
                                               float* __restrict__ Cf,
                                               const float* __restrict__ resid,
                                               const float* __restrict__ scale,
                                               const float* __restrict__ cosv,
                                               const float* __restrict__ sinv) {
    __shared__ alignas(16) __bf16 As[TM][32];
    __shared__ alignas(16) __bf16 Bs[128][32];
    constexpr int MI = TM / 32;
    int m0 = blockIdx.y * TM, n0 = blockIdx.x * 128;
    int tid = threadIdx.x;
    int lane = tid & 63, w = tid >> 6;
    int wm = (w >> 1) * (TM / 2), wn = (w & 1) * 64;
    int lr = lane & 15, lkg = lane >> 4, lk = lkg * 8;
    f32x4 acc[MI][4] = {};
    int nkt = K >> 5;
    for (int kt = 0; kt < nkt; ++kt) {
        __syncthreads();
#pragma unroll
        for (int i = 0; i < (TM * 4) / 256; ++i) {
            int c = i * 256 + tid;
            int row = c >> 2, k8 = (c & 3) << 3;
            gload16(&A[(size_t)(m0 + row) * K + kt * 32 + k8], &As[row][k8]);
        }
#pragma unroll
        for (int i = 0; i < 2; ++i) {
            int c = i * 256 + tid;
            int row = c >> 2, k8 = (c & 3) << 3;
            gload16(&Bt[(size_t)(n0 + row) * K + kt * 32 + k8], &Bs[row][k8]);
        }
        __syncthreads();
        bf16x8 af[MI], bfv[4];
#pragma unroll
        for (int mi = 0; mi < MI; ++mi) af[mi] = *(const bf16x8*)&As[wm + mi * 16 + lr][lk];
#pragma unroll
        for (int ni = 0; ni < 4; ++ni) bfv[ni] = *(const bf16x8*)&Bs[wn + ni * 16 + lr][lk];
#pragma unroll
        for (int mi = 0; mi < MI; ++mi)
#pragma unroll
            for (int ni = 0; ni < 4; ++ni)
                acc[mi][ni] = __builtin_amdgcn_mfma_f32_16x16x32_bf16(
                    af[mi], bfv[ni], acc[mi][ni], 0, 0, 0);
    }
    if (EPI == 1) {
        bool do_rope = (n0 + wn) < 2048;
        float qf = (n0 + wn) < 1024 ? QSCALE : 1.0f;
#pragma unroll
        for (int mi = 0; mi < MI; ++mi)
#pragma unroll
            for (int r = 0; r < 4; ++r) {
                int row = m0 + wm + mi * 16 + lkg * 4 + r;
                int s = row & (SEQ - 1);
#pragma unroll
                for (int ni = 0; ni < 2; ++ni) {
                    float v1 = acc[mi][ni][r], v2 = acc[mi][ni + 2][r];
                    size_t i1 = (size_t)row * N + n0 + wn + ni * 16 + lr;
                    size_t i2 = i1 + 32;
                    if (do_rope) {
                        int d = ni * 16 + lr;
                        float c = cosv[s * 32 + d], sn = sinv[s * 32 + d];
                        Cb[i1] = (__bf16)((v1 * c - v2 * sn) * qf);
                        Cb[i2] = (__bf16)((v2 * c + v1 * sn) * qf);
                    } else {
                        Cb[i1] = (__bf16)v1;
                        Cb[i2] = (__bf16)v2;
                    }
                }
            }
    } else if (EPI == 3) {
#pragma unroll
        for (int mi = 0; mi < MI; ++mi)
#pragma unroll
            for (int r = 0; r < 4; ++r) {
                int row = m0 + wm + mi * 16 + lkg * 4 + r;
#pragma unroll
                for (int ni = 0; ni < 4; ni += 2) {
                    float g = acc[mi][ni][r], u = acc[mi][ni + 1][r];
                    float mv = (g / (1.0f + __expf(-g))) * u;
                    int j = (((n0 + wn + ni * 16) >> 5) << 4) + lr;
                    Cb[(size_t)row * 1024 + j] = (__bf16)mv;
                }
            }
    } else {
#pragma unroll
        for (int mi = 0; mi < MI; ++mi)
#pragma unroll
            for (int ni = 0; ni < 4; ++ni)
#pragma unroll
                for (int r = 0; r < 4; ++r) {
                    int row = m0 + wm + mi * 16 + lkg * 4 + r;
                    int col = n0 + wn + ni * 16 + lr;
                    size_t idx = (size_t)row * N + col;
                    float vv = acc[mi][ni][r];
                    if (EPI == 0) Cb[idx] = (__bf16)vv;
                    else          Cf[idx] = resid[idx] + vv * scale[col];
                }
    }
}

// ---------------- causal flash attention ----------------
// grid = (NB*NHEAD, 16). Block handles q-tiles {y, 31-y}: 33 K-tiles each
// (perfect balance). 4 waves x 16 q-rows, KVBLK=64, exp2-domain softmax,
// l via ones-column MFMA, defer-max rescale, diagonal-only masking.
__global__ __launch_bounds__(256) void attn_k(const __bf16* __restrict__ qkv,
                                              __bf16* __restrict__ outp) {
    __shared__ alignas(16) __bf16 KtF[64 * 64];        // [key][d] slot-swizzled
    __shared__ alignas(16) __bf16 VtF[80 * 64];        // [d][key]; rows 64.. = ones/zeros
    __shared__ alignas(16) __bf16 PlF[4 * 16 * 64];    // per-wave P, swizzled
    int bh = blockIdx.x;
    int b = bh >> 4, h = bh & 15;
    int tid = threadIdx.x, lane = tid & 63, w = tid >> 6;
    int lr = lane & 15, lkg = lane >> 4, lk = lkg * 8;
    int l7 = lr & 7;
    size_t tokb = (size_t)b * SEQ;

    // ones row (d=64) + zero rows for the l-accumulator MFMA tile
#pragma unroll
    for (int j = 0; j < 4; ++j) {
        int off = tid * 4 + j;
        VtF[64 * 64 + off] = (off < 64) ? (__bf16)1.0f : (__bf16)0.0f;
    }

    for (int half = 0; half < 2; ++half) {
        int qb = half ? (31 - blockIdx.y) : (int)blockIdx.y;
        int qr0 = qb * 64 + w * 16;

        bf16x8 aq[2];
#pragma unroll
        for (int ks = 0; ks < 2; ++ks)
            aq[ks] = *(const bf16x8*)&qkv[(tokb + qr0 + lr) * QKVN + h * 64 + ks * 32 + lk];

        f32x4 oa[4] = {};
        f32x4 ol = {};
        float m_run[4];
#pragma unroll
        for (int r = 0; r < 4; ++r) m_run[r] = -1e30f;

        int nkb = qb + 1;
        for (int kb = 0; kb < nkb; ++kb) {
            __syncthreads();
            // K tile via global_load_lds, source pre-swizzled
#pragma unroll
            for (int i = 0; i < 2; ++i) {
                int c = i * 256 + tid;
                int kr = c >> 3, s = c & 7;
                gload16(&qkv[(tokb + kb * 64 + kr) * QKVN + 1024 + h * 64 + ((s ^ (kr & 7)) << 3)],
                        &KtF[c * 8]);
            }
            // V tile transposed, conflict-free swizzled scalar writes
            {
                int key = lane;
                int kslot = key >> 3, ke = key & 7;
#pragma unroll
                for (int i = 0; i < 2; ++i) {
                    int ch = w * 2 + i;
                    uint4 vv = *(const uint4*)&qkv[(tokb + kb * 64 + key) * QKVN + 2048 + h * 64 + ch * 8];
                    const __bf16* ve = (const __bf16*)&vv;
#pragma unroll
                    for (int j = 0; j < 8; ++j)
                        VtF[(ch * 8 + j) * 64 + ((kslot ^ j) << 3) + ke] = ve[j];
                }
            }
            __syncthreads();

            // QK^T (q pre-scaled by 0.125*log2e -> scores already in exp2 domain)
            f32x4 sc[4] = {};
#pragma unroll
            for (int jt = 0; jt < 4; ++jt)
#pragma unroll
                for (int ks = 0; ks < 2; ++ks) {
                    bf16x8 bk = *(const bf16x8*)&KtF[(jt * 16 + lr) * 64 + (((ks * 4 + lkg) ^ l7) << 3)];
                    sc[jt] = __builtin_amdgcn_mfma_f32_16x16x32_bf16(aq[ks], bk, sc[jt], 0, 0, 0);
                }
            // causal mask: only the diagonal tile needs it (wave-uniform test)
            if (kb * 64 + 63 > qr0) {
#pragma unroll
                for (int jt = 0; jt < 4; ++jt)
#pragma unroll
                    for (int r = 0; r < 4; ++r) {
                        int q = qr0 + lkg * 4 + r;
                        int key = kb * 64 + jt * 16 + lr;
                        if (key > q) sc[jt][r] = -1e9f;
                    }
            }
            // row max (16-lane reduce) + defer-max vote
            float pmax[4];
            bool need = false;
#pragma unroll
            for (int r = 0; r < 4; ++r) {
                float v = fmaxf(fmaxf(sc[0][r], sc[1][r]), fmaxf(sc[2][r], sc[3][r]));
                v = fmaxf(v, __shfl_xor(v, 1));
                v = fmaxf(v, __shfl_xor(v, 2));
                v = fmaxf(v, __shfl_xor(v, 4));
                v = fmaxf(v, __shfl_xor(v, 8));
                pmax[r] = v;
                need = need || (v > m_run[r] + 8.0f);
            }
            if (__any(need)) {
#pragma unroll
                for (int r = 0; r < 4; ++r) {
                    float mn = fmaxf(m_run[r], pmax[r]);
                    float al = exp2f(m_run[r] - mn);
                    m_run[r] = mn;
#pragma unroll
                    for (int dt = 0; dt < 4; ++dt) oa[dt][r] *= al;
                    ol[r] *= al;
                }
            }
            // P = exp2(s - m)
#pragma unroll
            for (int jt = 0; jt < 4; ++jt)
#pragma unroll
                for (int r = 0; r < 4; ++r)
                    sc[jt][r] = exp2f(sc[jt][r] - m_run[r]);
            // P -> LDS (per-wave, swizzled)
#pragma unroll
            for (int jt = 0; jt < 4; ++jt)
#pragma unroll
                for (int r = 0; r < 4; ++r) {
                    int rowp = lkg * 4 + r;
                    PlF[w * 1024 + rowp * 64 + (((jt * 2 + (lr >> 3)) ^ (rowp & 7)) << 3) + l7] =
                        (__bf16)sc[jt][r];
                }
            asm volatile("s_waitcnt lgkmcnt(0)" ::: "memory");
            __builtin_amdgcn_sched_barrier(0);
            // P·V (+ ones-column l tile)
#pragma unroll
            for (int ks2 = 0; ks2 < 2; ++ks2) {
                bf16x8 ap = *(const bf16x8*)&PlF[w * 1024 + lr * 64 + (((ks2 * 4 + lkg) ^ l7) << 3)];
#pragma unroll
                for (int dt = 0; dt < 4; ++dt) {
                    bf16x8 bv = *(const bf16x8*)&VtF[(dt * 16 + lr) * 64 + (((ks2 * 4 + lkg) ^ l7) << 3)];
                    oa[dt] = __builtin_amdgcn_mfma_f32_16x16x32_bf16(ap, bv, oa[dt], 0, 0, 0);
                }
                bf16x8 bo = *(const bf16x8*)&VtF[(64 + lr) * 64 + (((ks2 * 4 + lkg) ^ l7) << 3)];
                ol = __builtin_amdgcn_mfma_f32_16x16x32_bf16(ap, bo, ol, 0, 0, 0);
            }
        }
        // epilogue: l lives in lr==0 lane of each 16-lane group
#pragma unroll
        for (int r = 0; r < 4; ++r) {
            float l = __shfl(ol[r], lane & 48);
            float inv = 1.0f / l;
            int row = qr0 + lkg * 4 + r;
#pragma unroll
            for (int dt = 0; dt < 4; ++dt)
                outp[(tokb + row) * 1024 + h * 64 + dt * 16 + lr] =
                    (__bf16)(oa[dt][r] * inv);
        }
    }
}

// ---------------- launch ----------------
extern "C" void kernel_launch(void* const* d_in, const int* in_sizes, int n_in,
                              void* d_out, int out_size, void* d_ws, size_t ws_size,
                              hipStream_t stream) {
    const float* x       = (const float*)d_in[0];
    const float* cosv    = (const float*)d_in[1];
    const float* sinv    = (const float*)d_in[2];
    const float* wq      = (const float*)d_in[4];
    const float* wk      = (const float*)d_in[5];
    const float* wv      = (const float*)d_in[6];
    const float* wo      = (const float*)d_in[7];
    const float* wgate   = (const float*)d_in[8];
    const float* wup     = (const float*)d_in[9];
    const float* wdown   = (const float*)d_in[10];
    const float* norm1   = (const float*)d_in[11];
    const float* norm2   = (const float*)d_in[12];
    const float* ls_attn = (const float*)d_in[13];
    const float* ls_mlp  = (const float*)d_in[14];

    char* ws = (char*)d_ws;
    __bf16* wqkvT = (__bf16*)(ws + OFF_WQKVT);
    __bf16* woT   = (__bf16*)(ws + OFF_WOT);
    __bf16* wguT  = (__bf16*)(ws + OFF_WGUT);
    __bf16* wdT   = (__bf16*)(ws + OFF_WDT);
    __bf16* hb    = (__bf16*)(ws + OFF_HB);
    __bf16* qkvb  = (__bf16*)(ws + OFF_QKV);
    __bf16* attnb = (__bf16*)(ws + OFF_ATTN);
    float*  h2    = (float*)(ws + OFF_H2);
    __bf16* gb    = (__bf16*)(ws + OFF_G);
    __bf16* mb    = (__bf16*)(ws + OFF_M);
    float*  outf  = (float*)d_out;

    transpose_all_k<<<dim3(512, 7), 256, 0, stream>>>(
        wq, wk, wv, wo, wgate, wup, wdown, wqkvT, woT, wguT, wdT);

    rmsnorm_k<<<NTOK, 256, 0, stream>>>(x, norm1, hb);
    gemm_bt<1, 128><<<dim3(QKVN / 128, NTOK / 128), 256, 0, stream>>>(
        hb, wqkvT, NTOK, QKVN, 512, qkvb, nullptr, nullptr, nullptr, cosv, sinv);
    attn_k<<<dim3(NB * NHEAD, 16), 256, 0, stream>>>(qkvb, attnb);
    gemm_bt<2, 64><<<dim3(HIDD / 128, NTOK / 64), 256, 0, stream>>>(
        attnb, woT, NTOK, HIDD, 1024, nullptr, h2, x, ls_attn, nullptr, nullptr);
    rmsnorm_k<<<NTOK, 256, 0, stream>>>(h2, norm2, gb);
    gemm_bt<3, 128><<<dim3(GUN / 128, NTOK / 128), 256, 0, stream>>>(
        gb, wguT, NTOK, GUN, 512, mb, nullptr, nullptr, nullptr, nullptr, nullptr);
    gemm_bt<2, 64><<<dim3(HIDD / 128, NTOK / 64), 256, 0, stream>>>(
        mb, wdT, NTOK, HIDD, 1024, nullptr, outf, h2, ls_mlp, nullptr, nullptr);
}

// Round 4
// 154.072 us; speedup vs baseline: 1.9609x; 1.1440x over previous
//
#include <hip/hip_runtime.h>
#include <hip/hip_bf16.h>

typedef __bf16 bf16x8 __attribute__((ext_vector_type(8)));
typedef __bf16 bf16x4 __attribute__((ext_vector_type(4)));
typedef float f32x4 __attribute__((ext_vector_type(4)));

#define SEQ   2048
#define NB    2
#define NTOK  4096
#define HIDD  512
#define NHEAD 16
#define DHEAD 64
#define QKVN  3072
#define GUN   2048

// workspace layout (bytes)
#define OFF_WQKVT  0u
#define OFF_WOT    3145728u
#define OFF_WGUT   4194304u
#define OFF_WDT    6291456u
#define OFF_HB     7340032u
#define OFF_QKV    11534336u
#define OFF_ATTN   36700160u
#define OFF_H2     45088768u
#define OFF_G      53477376u
#define OFF_M      (OFF_QKV + 16777216u)

#define QSCALE 0.1803368801111731f          // 0.125 * log2(e): exp2-domain scores

typedef unsigned int __attribute__((address_space(1))) as1_uint;
typedef unsigned int __attribute__((address_space(3))) as3_uint;
__device__ __forceinline__ void gload16(const void* g, void* l) {
    __builtin_amdgcn_global_load_lds((const as1_uint*)g, (as3_uint*)l, 16, 0, 0);
}

// ---------------- all 7 weight transposes in one launch ----------------
__global__ __launch_bounds__(256) void transpose_all_k(
    const float* __restrict__ wq, const float* __restrict__ wk,
    const float* __restrict__ wv, const float* __restrict__ wo,
    const float* __restrict__ wg, const float* __restrict__ wu,
    const float* __restrict__ wd,
    __bf16* __restrict__ qkvT, __bf16* __restrict__ woT,
    __bf16* __restrict__ wguT, __bf16* __restrict__ wdT) {
    __shared__ float t[32][33];
    int which = blockIdx.y;
    const float* in; __bf16* out; int K, N, mode = 0, phase = 0;
    switch (which) {
        case 0: in = wq; out = qkvT;              K = 512;  N = 1024; break;
        case 1: in = wk; out = qkvT + 1024 * 512; K = 512;  N = 1024; break;
        case 2: in = wv; out = qkvT + 2048 * 512; K = 512;  N = 1024; break;
        case 3: in = wo; out = woT;               K = 1024; N = 512;  break;
        case 4: in = wg; out = wguT;              K = 512;  N = 1024; mode = 1; phase = 0; break;
        case 5: in = wu; out = wguT;              K = 512;  N = 1024; mode = 1; phase = 1; break;
        default: in = wd; out = wdT;              K = 1024; N = 512;  break;
    }
    int ntn = N >> 5;
    int n0 = (blockIdx.x & (ntn - 1)) * 32;
    int k0 = (blockIdx.x / ntn) * 32;
    int tx = threadIdx.x & 31, ty = threadIdx.x >> 5;
#pragma unroll
    for (int j = 0; j < 4; ++j)
        t[ty * 4 + j][tx] = in[(size_t)(k0 + ty * 4 + j) * N + n0 + tx];
    __syncthreads();
#pragma unroll
    for (int j = 0; j < 4; ++j) {
        int n = n0 + ty * 4 + j;
        int row = mode ? (((n >> 4) << 5) + phase * 16 + (n & 15)) : n;
        out[(size_t)row * K + k0 + tx] = (__bf16)t[tx][ty * 4 + j];
    }
}

// ---------------- RMSNorm ----------------
__global__ __launch_bounds__(256) void rmsnorm_k(const float* __restrict__ x,
                                                 const float* __restrict__ w,
                                                 __bf16* __restrict__ out) {
    int row = blockIdx.x;
    int t = threadIdx.x;
    const float* xr = x + (size_t)row * HIDD;
    float2 v = *(const float2*)&xr[t * 2];
    float ss = v.x * v.x + v.y * v.y;
#pragma unroll
    for (int off = 32; off >= 1; off >>= 1) ss += __shfl_xor(ss, off);
    __shared__ float red[4];
    if ((t & 63) == 0) red[t >> 6] = ss;
    __syncthreads();
    float tot = red[0] + red[1] + red[2] + red[3];
    float r = rsqrtf(tot * (1.0f / HIDD) + 1e-8f);
    out[(size_t)row * HIDD + t * 2]     = (__bf16)(v.x * r * w[t * 2]);
    out[(size_t)row * HIDD + t * 2 + 1] = (__bf16)(v.y * r * w[t * 2 + 1]);
}

// ---------------- GEMM: C[M][N] = A[M][K] * Bt[N][K]^T ----------------
template <int EPI, int TM, int TN>
__global__ __launch_bounds__(256) void gemm_bt(const __bf16* __restrict__ A,
                                               const __bf16* __restrict__ Bt,
                                               int M, int N, int K,
                                               __bf16* __restrict__ Cb,
                                               float* __restrict__ Cf,
                                               const float* __restrict__ resid,
                                               const float* __restrict__ scale,
                                               const float* __restrict__ cosv,
                                               const float* __restrict__ sinv) {
    __shared__ alignas(16) __bf16 As[TM][32];
    __shared__ alignas(16) __bf16 Bs[TN][32];
    constexpr int MI = TM / 32, NI = TN / 32;
    int m0 = blockIdx.y * TM, n0 = blockIdx.x * TN;
    int tid = threadIdx.x;
    int lane = tid & 63, w = tid >> 6;
    int wm = (w >> 1) * (TM / 2), wn = (w & 1) * (TN / 2);
    int lr = lane & 15, lkg = lane >> 4, lk = lkg * 8;
    f32x4 acc[MI][NI] = {};
    int nkt = K >> 5;
    for (int kt = 0; kt < nkt; ++kt) {
        __syncthreads();
#pragma unroll
        for (int i = 0; i < (TM * 4) / 256; ++i) {
            int c = i * 256 + tid;
            int row = c >> 2, k8 = (c & 3) << 3;
            gload16(&A[(size_t)(m0 + row) * K + kt * 32 + k8], &As[row][k8]);
        }
#pragma unroll
        for (int i = 0; i < (TN * 4) / 256; ++i) {
            int c = i * 256 + tid;
            int row = c >> 2, k8 = (c & 3) << 3;
            gload16(&Bt[(size_t)(n0 + row) * K + kt * 32 + k8], &Bs[row][k8]);
        }
        __syncthreads();
        bf16x8 af[MI], bfv[NI];
#pragma unroll
        for (int mi = 0; mi < MI; ++mi) af[mi] = *(const bf16x8*)&As[wm + mi * 16 + lr][lk];
#pragma unroll
        for (int ni = 0; ni < NI; ++ni) bfv[ni] = *(const bf16x8*)&Bs[wn + ni * 16 + lr][lk];
#pragma unroll
        for (int mi = 0; mi < MI; ++mi)
#pragma unroll
            for (int ni = 0; ni < NI; ++ni)
                acc[mi][ni] = __builtin_amdgcn_mfma_f32_16x16x32_bf16(
                    af[mi], bfv[ni], acc[mi][ni], 0, 0, 0);
    }
    if (EPI == 1) {
        bool do_rope = (n0 + wn) < 2048;
        float qf = (n0 + wn) < 1024 ? QSCALE : 1.0f;
#pragma unroll
        for (int mi = 0; mi < MI; ++mi)
#pragma unroll
            for (int r = 0; r < 4; ++r) {
                int row = m0 + wm + mi * 16 + lkg * 4 + r;
                int s = row & (SEQ - 1);
#pragma unroll
                for (int ni = 0; ni < 2; ++ni) {
                    float v1 = acc[mi][ni][r], v2 = acc[mi][ni + 2][r];
                    size_t i1 = (size_t)row * N + n0 + wn + ni * 16 + lr;
                    size_t i2 = i1 + 32;
                    if (do_rope) {
                        int d = ni * 16 + lr;
                        float c = cosv[s * 32 + d], sn = sinv[s * 32 + d];
                        Cb[i1] = (__bf16)((v1 * c - v2 * sn) * qf);
                        Cb[i2] = (__bf16)((v2 * c + v1 * sn) * qf);
                    } else {
                        Cb[i1] = (__bf16)v1;
                        Cb[i2] = (__bf16)v2;
                    }
                }
            }
    } else if (EPI == 3) {
#pragma unroll
        for (int mi = 0; mi < MI; ++mi)
#pragma unroll
            for (int r = 0; r < 4; ++r) {
                int row = m0 + wm + mi * 16 + lkg * 4 + r;
#pragma unroll
                for (int ni = 0; ni < 4; ni += 2) {
                    float g = acc[mi][ni][r], u = acc[mi][ni + 1][r];
                    float mv = (g / (1.0f + __expf(-g))) * u;
                    int j = (((n0 + wn + ni * 16) >> 5) << 4) + lr;
                    Cb[(size_t)row * 1024 + j] = (__bf16)mv;
                }
            }
    } else {
#pragma unroll
        for (int mi = 0; mi < MI; ++mi)
#pragma unroll
            for (int ni = 0; ni < NI; ++ni)
#pragma unroll
                for (int r = 0; r < 4; ++r) {
                    int row = m0 + wm + mi * 16 + lkg * 4 + r;
                    int col = n0 + wn + ni * 16 + lr;
                    size_t idx = (size_t)row * N + col;
                    float vv = acc[mi][ni][r];
                    if (EPI == 0) Cb[idx] = (__bf16)vv;
                    else          Cf[idx] = resid[idx] + vv * scale[col];
                }
    }
}

// ---------------- causal flash attention ----------------
// grid = (NB*NHEAD, 32), heavy-first. 4 waves x 16 q-rows, KVBLK=64.
// Swapped-operand MFMAs: lane owns q = lane&15 throughout; P in registers.
// Double-buffered K/V staging: loads for kb+1 issue before compute of kb.
__global__ __launch_bounds__(256, 4) void attn_k(const __bf16* __restrict__ qkv,
                                                 __bf16* __restrict__ outp) {
    __shared__ alignas(16) __bf16 KtF[2][64 * 64];   // [key][d], source-swizzled
    __shared__ alignas(16) __bf16 VtF[2][64 * 64];   // [dv][pi-key], swizzled
    int bh = blockIdx.x;
    int b = bh >> 4, h = bh & 15;
    int qb = 31 - (int)blockIdx.y;                   // heavy blocks first
    int tid = threadIdx.x, lane = tid & 63, w = tid >> 6;
    int lq = lane & 15, g = lane >> 4;
    int qr0 = qb * 64 + w * 16;
    size_t tokb = (size_t)b * SEQ;

    // V staging constants: lane owns key = lane; pi-position slot/elem
    int vkey = lane;
    int vslot = ((vkey >> 5) << 2) + ((vkey >> 2) & 3);   // 4*ks2 + g'
    int vke   = (((vkey >> 4) & 1) << 2) + (vkey & 3);    // 4*u + r

    // Q as B-fragment: Q[q=lq][d = ks*32 + 8g + e]
    bf16x8 aq[2];
#pragma unroll
    for (int ks = 0; ks < 2; ++ks)
        aq[ks] = *(const bf16x8*)&qkv[(tokb + qr0 + lq) * QKVN + h * 64 + ks * 32 + g * 8];

    f32x4 oa[4] = {};
    float m_run = -1e30f, l_part = 0.0f;
    uint4 vv0, vv1;
    int nkb = qb + 1;
    int cur = 0;

    // ---- prologue: stage tile 0 into buf 0 ----
#pragma unroll
    for (int i = 0; i < 2; ++i) {
        int c = i * 256 + tid;
        int kr = c >> 3, s = c & 7;
        gload16(&qkv[(tokb + kr) * QKVN + 1024 + h * 64 + ((s ^ (kr & 7)) << 3)],
                &KtF[0][c * 8]);
    }
    vv0 = *(const uint4*)&qkv[(tokb + vkey) * QKVN + 2048 + h * 64 + (w * 2) * 8];
    vv1 = *(const uint4*)&qkv[(tokb + vkey) * QKVN + 2048 + h * 64 + (w * 2 + 1) * 8];
    {
        const __bf16* ve0 = (const __bf16*)&vv0;
        const __bf16* ve1 = (const __bf16*)&vv1;
#pragma unroll
        for (int j = 0; j < 8; ++j) {
            int dv0 = (w * 2) * 8 + j, dv1 = (w * 2 + 1) * 8 + j;
            VtF[0][dv0 * 64 + ((vslot ^ j) << 3) + vke] = ve0[j];
            VtF[0][dv1 * 64 + ((vslot ^ j) << 3) + vke] = ve1[j];
        }
    }
    __syncthreads();

    for (int kb = 0; kb < nkb; ++kb) {
        bool pf = (kb + 1) < nkb;
        if (pf) {  // issue next tile's loads (hide latency under compute)
#pragma unroll
            for (int i = 0; i < 2; ++i) {
                int c = i * 256 + tid;
                int kr = c >> 3, s = c & 7;
                gload16(&qkv[(tokb + (kb + 1) * 64 + kr) * QKVN + 1024 + h * 64 + ((s ^ (kr & 7)) << 3)],
                        &KtF[cur ^ 1][c * 8]);
            }
            vv0 = *(const uint4*)&qkv[(tokb + (kb + 1) * 64 + vkey) * QKVN + 2048 + h * 64 + (w * 2) * 8];
            vv1 = *(const uint4*)&qkv[(tokb + (kb + 1) * 64 + vkey) * QKVN + 2048 + h * 64 + (w * 2 + 1) * 8];
        }

        // ---- QK^T swapped: sc[jt] = K_tile · Q  -> lane holds S[key][q=lq]
        f32x4 sc[4] = {};
        __builtin_amdgcn_s_setprio(1);
#pragma unroll
        for (int jt = 0; jt < 4; ++jt)
#pragma unroll
            for (int ks = 0; ks < 2; ++ks) {
                bf16x8 bk = *(const bf16x8*)&KtF[cur][(jt * 16 + lq) * 64 + (((ks * 4 + g) ^ (lq & 7)) << 3)];
                sc[jt] = __builtin_amdgcn_mfma_f32_16x16x32_bf16(bk, aq[ks], sc[jt], 0, 0, 0);
            }
        __builtin_amdgcn_s_setprio(0);

        // causal mask (diagonal tile only; wave-uniform branch)
        if (kb * 64 + 63 > qr0) {
            int qabs = qr0 + lq;
#pragma unroll
            for (int jt = 0; jt < 4; ++jt)
#pragma unroll
                for (int r = 0; r < 4; ++r) {
                    int key = kb * 64 + jt * 16 + g * 4 + r;
                    if (key > qabs) sc[jt][r] = -1e9f;
                }
        }

        // row max over 16 local + 2 shuffles (lanes sharing q = lane&15)
        float m0 = fmaxf(fmaxf(sc[0][0], sc[0][1]), fmaxf(sc[0][2], sc[0][3]));
        float m1 = fmaxf(fmaxf(sc[1][0], sc[1][1]), fmaxf(sc[1][2], sc[1][3]));
        float m2 = fmaxf(fmaxf(sc[2][0], sc[2][1]), fmaxf(sc[2][2], sc[2][3]));
        float m3 = fmaxf(fmaxf(sc[3][0], sc[3][1]), fmaxf(sc[3][2], sc[3][3]));
        float mx = fmaxf(fmaxf(m0, m1), fmaxf(m2, m3));
        mx = fmaxf(mx, __shfl_xor(mx, 16));
        mx = fmaxf(mx, __shfl_xor(mx, 32));
        // defer-max (THR = 8 octaves)
        if (__any(mx > m_run + 8.0f)) {
            float mn = fmaxf(m_run, mx);
            float al = exp2f(m_run - mn);
            m_run = mn;
#pragma unroll
            for (int dt = 0; dt < 4; ++dt) oa[dt] *= al;
            l_part *= al;
        }
        // P = exp2(s - m); local partial sum (row-reduce deferred to epilogue)
#pragma unroll
        for (int jt = 0; jt < 4; ++jt)
#pragma unroll
            for (int r = 0; r < 4; ++r) {
                float p = exp2f(sc[jt][r] - m_run);
                sc[jt][r] = p;
                l_part += p;
            }

        // ---- PV swapped: oa[dt] += V^T_tile · P^T ; P-frags from registers
        __builtin_amdgcn_s_setprio(1);
#pragma unroll
        for (int ks2 = 0; ks2 < 2; ++ks2) {
            bf16x8 pfv;
#pragma unroll
            for (int e = 0; e < 4; ++e) {
                pfv[e]     = (__bf16)sc[2 * ks2][e];
                pfv[e + 4] = (__bf16)sc[2 * ks2 + 1][e];
            }
#pragma unroll
            for (int dt = 0; dt < 4; ++dt) {
                bf16x8 av = *(const bf16x8*)&VtF[cur][(dt * 16 + lq) * 64 + (((ks2 * 4 + g) ^ (lq & 7)) << 3)];
                oa[dt] = __builtin_amdgcn_mfma_f32_16x16x32_bf16(av, pfv, oa[dt], 0, 0, 0);
            }
        }
        __builtin_amdgcn_s_setprio(0);

        if (pf) {  // write staged V (loads have had the whole compute to land)
            const __bf16* ve0 = (const __bf16*)&vv0;
            const __bf16* ve1 = (const __bf16*)&vv1;
#pragma unroll
            for (int j = 0; j < 8; ++j) {
                int dv0 = (w * 2) * 8 + j, dv1 = (w * 2 + 1) * 8 + j;
                VtF[cur ^ 1][dv0 * 64 + ((vslot ^ j) << 3) + vke] = ve0[j];
                VtF[cur ^ 1][dv1 * 64 + ((vslot ^ j) << 3) + vke] = ve1[j];
            }
        }
        __syncthreads();
        cur ^= 1;
    }

    // epilogue: row-sum reduce, normalize, packed b64 stores
    l_part += __shfl_xor(l_part, 16);
    l_part += __shfl_xor(l_part, 32);
    float inv = 1.0f / l_part;
#pragma unroll
    for (int dt = 0; dt < 4; ++dt) {
        bf16x4 ov;
#pragma unroll
        for (int r = 0; r < 4; ++r) ov[r] = (__bf16)(oa[dt][r] * inv);
        *(bf16x4*)&outp[(tokb + qr0 + lq) * 1024 + h * 64 + dt * 16 + g * 4] = ov;
    }
}

// ---------------- launch ----------------
extern "C" void kernel_launch(void* const* d_in, const int* in_sizes, int n_in,
                              void* d_out, int out_size, void* d_ws, size_t ws_size,
                              hipStream_t stream) {
    const float* x       = (const float*)d_in[0];
    const float* cosv    = (const float*)d_in[1];
    const float* sinv    = (const float*)d_in[2];
    const float* wq      = (const float*)d_in[4];
    const float* wk      = (const float*)d_in[5];
    const float* wv      = (const float*)d_in[6];
    const float* wo      = (const float*)d_in[7];
    const float* wgate   = (const float*)d_in[8];
    const float* wup     = (const float*)d_in[9];
    const float* wdown   = (const float*)d_in[10];
    const float* norm1   = (const float*)d_in[11];
    const float* norm2   = (const float*)d_in[12];
    const float* ls_attn = (const float*)d_in[13];
    const float* ls_mlp  = (const float*)d_in[14];

    char* ws = (char*)d_ws;
    __bf16* wqkvT = (__bf16*)(ws + OFF_WQKVT);
    __bf16* woT   = (__bf16*)(ws + OFF_WOT);
    __bf16* wguT  = (__bf16*)(ws + OFF_WGUT);
    __bf16* wdT   = (__bf16*)(ws + OFF_WDT);
    __bf16* hb    = (__bf16*)(ws + OFF_HB);
    __bf16* qkvb  = (__bf16*)(ws + OFF_QKV);
    __bf16* attnb = (__bf16*)(ws + OFF_ATTN);
    float*  h2    = (float*)(ws + OFF_H2);
    __bf16* gb    = (__bf16*)(ws + OFF_G);
    __bf16* mb    = (__bf16*)(ws + OFF_M);
    float*  outf  = (float*)d_out;

    transpose_all_k<<<dim3(512, 7), 256, 0, stream>>>(
        wq, wk, wv, wo, wgate, wup, wdown, wqkvT, woT, wguT, wdT);

    rmsnorm_k<<<NTOK, 256, 0, stream>>>(x, norm1, hb);
    gemm_bt<1, 128, 128><<<dim3(QKVN / 128, NTOK / 128), 256, 0, stream>>>(
        hb, wqkvT, NTOK, QKVN, 512, qkvb, nullptr, nullptr, nullptr, cosv, sinv);
    attn_k<<<dim3(NB * NHEAD, 32), 256, 0, stream>>>(qkvb, attnb);
    gemm_bt<2, 64, 64><<<dim3(HIDD / 64, NTOK / 64), 256, 0, stream>>>(
        attnb, woT, NTOK, HIDD, 1024, nullptr, h2, x, ls_attn, nullptr, nullptr);
    rmsnorm_k<<<NTOK, 256, 0, stream>>>(h2, norm2, gb);
    gemm_bt<3, 128, 128><<<dim3(GUN / 128, NTOK / 128), 256, 0, stream>>>(
        gb, wguT, NTOK, GUN, 512, mb, nullptr, nullptr, nullptr, nullptr, nullptr);
    gemm_bt<2, 64, 64><<<dim3(HIDD / 64, NTOK / 64), 256, 0, stream>>>(
        mb, wdT, NTOK, HIDD, 1024, nullptr, outf, h2, ls_mlp, nullptr, nullptr);
}